// Round 9
// baseline (8687.816 us; speedup 1.0000x reference)
//
#include <hip/hip_runtime.h>
#include <math.h>

#define TOKENS 16384
#define DIM    7168
#define NEXP   256
#define TK     8
#define BM     64
#define BK     32
#define NKT    (DIM / BK)   /* 224 */
#define DELTA  8.0e-3f
#define MAXC   12

/* K1 LDS (floats):
   Xs[2][64][36] @0      : rows 16B-aligned, reads are near-broadcast
   Ws[2][32][260] @4608  : [k][expert]-major -> contiguous b128 reads
   Epilogue overlay lgf[64][260] = 16640 fl <= 21248. */
#define XOFF(b)      ((b) * 2304)
#define WOFF(b)      (4608 + (b) * 8320)
#define K1_LDS_BYTES (21248 * 4)

/* ws layout (bytes): cand[16384][16] ints, cnt, m, invs */
#define WS_CAND 0
#define WS_CNT  (TOKENS * 16 * 4)
#define WS_M    (WS_CNT + TOKENS * 4)
#define WS_INVS (WS_M + TOKENS * 4)

__global__ __launch_bounds__(256, 2)
void gate_gemm(const float* __restrict__ x, const float* __restrict__ w,
               int* __restrict__ wsCand, int* __restrict__ wsCnt,
               float* __restrict__ wsM, float* __restrict__ wsInvs)
{
    extern __shared__ __align__(16) float smem[];
    const int t    = threadIdx.x;
    const int tx   = t & 31;     /* experts 4*tx+q and 128+4*tx+q */
    const int ty   = t >> 5;     /* tokens  ty*8 + i              */
    const int lane = t & 63;
    const int wv   = t >> 6;
    const int tok0 = blockIdx.x * BM;

    /* staging maps */
    const int xr = t >> 2;           /* x row 0..63, 4 threads/row  */
    const int xc = (t & 3) * 8;      /* 8 floats each               */
    const float* xp = x + (size_t)(tok0 + xr) * DIM + xc;
    const float* wp = w + (size_t)t * DIM;   /* one expert row per thread */

    float4 xs0, xs1, wr0, wr1, wr2, wr3, wr4, wr5, wr6, wr7;

#define LOADT(kt) do {                                          \
    const float* xq = xp + (size_t)(kt) * BK;                   \
    xs0 = *(const float4*)(xq);                                 \
    xs1 = *(const float4*)(xq + 4);                             \
    const float* wq = wp + (size_t)(kt) * BK;                   \
    wr0 = *(const float4*)(wq);      wr1 = *(const float4*)(wq + 4);  \
    wr2 = *(const float4*)(wq + 8);  wr3 = *(const float4*)(wq + 12); \
    wr4 = *(const float4*)(wq + 16); wr5 = *(const float4*)(wq + 20); \
    wr6 = *(const float4*)(wq + 24); wr7 = *(const float4*)(wq + 28); \
} while (0)

/* W transposed stash: Ws[k][t] (2-way bank = free) */
#define STW(Ww, i, v)                                           \
    (Ww)[(4*(i)+0)*260 + t] = (v).x;                            \
    (Ww)[(4*(i)+1)*260 + t] = (v).y;                            \
    (Ww)[(4*(i)+2)*260 + t] = (v).z;                            \
    (Ww)[(4*(i)+3)*260 + t] = (v).w;

#define STASH(buf) do {                                         \
    float* Xw = smem + XOFF(buf) + xr * 36 + xc;                \
    *(float4*)(Xw)     = xs0;                                   \
    *(float4*)(Xw + 4) = xs1;                                   \
    float* Ww = smem + WOFF(buf);                               \
    STW(Ww, 0, wr0) STW(Ww, 1, wr1) STW(Ww, 2, wr2)             \
    STW(Ww, 3, wr3) STW(Ww, 4, wr4) STW(Ww, 5, wr5)             \
    STW(Ww, 6, wr6) STW(Ww, 7, wr7)                             \
} while (0)

    float acc[8][8];   /* [token i][expert col j] */
    #pragma unroll
    for (int i = 0; i < 8; ++i)
        #pragma unroll
        for (int j = 0; j < 8; ++j)
            acc[i][j] = 0.0f;

    LOADT(0);
    STASH(0);
    __syncthreads();

    for (int kt = 0; kt < NKT; ++kt) {
        const int cur = kt & 1;
        if (kt + 1 < NKT) LOADT(kt + 1);
        const float* Xb = smem + XOFF(cur) + (ty * 8) * 36;
        const float* Wb = smem + WOFF(cur) + 4 * tx;
        #pragma unroll
        for (int s = 0; s < 8; ++s) {            /* 8 slabs of 4 k */
            float4 xf[8];
            #pragma unroll
            for (int i = 0; i < 8; ++i)
                xf[i] = *(const float4*)(Xb + i * 36 + s * 4);   /* broadcast */
            /* JIT W loads inside q-loop: only 2 float4 live at a time */
            #pragma unroll
            for (int q = 0; q < 4; ++q) {
                float4 wa = *(const float4*)(Wb + (s * 4 + q) * 260);
                float4 wb = *(const float4*)(Wb + (s * 4 + q) * 260 + 128);
                #pragma unroll
                for (int i = 0; i < 8; ++i) {
                    const float xi = (q == 0) ? xf[i].x : (q == 1) ? xf[i].y
                                   : (q == 2) ? xf[i].z : xf[i].w;
                    acc[i][0] = fmaf(xi, wa.x, acc[i][0]);
                    acc[i][1] = fmaf(xi, wa.y, acc[i][1]);
                    acc[i][2] = fmaf(xi, wa.z, acc[i][2]);
                    acc[i][3] = fmaf(xi, wa.w, acc[i][3]);
                    acc[i][4] = fmaf(xi, wb.x, acc[i][4]);
                    acc[i][5] = fmaf(xi, wb.y, acc[i][5]);
                    acc[i][6] = fmaf(xi, wb.z, acc[i][6]);
                    acc[i][7] = fmaf(xi, wb.w, acc[i][7]);
                }
            }
        }
        if (kt + 1 < NKT) STASH((kt + 1) & 1);
        __syncthreads();
    }

    /* ---- logits to LDS overlay [64][260]: b128 stores ---- */
    float* lgf = smem;
    #pragma unroll
    for (int i = 0; i < 8; ++i) {
        float* lr = lgf + (size_t)(ty * 8 + i) * 260 + 4 * tx;
        float4 v0, v1;
        v0.x = acc[i][0]; v0.y = acc[i][1]; v0.z = acc[i][2]; v0.w = acc[i][3];
        v1.x = acc[i][4]; v1.y = acc[i][5]; v1.z = acc[i][6]; v1.w = acc[i][7];
        *(float4*)(lr)       = v0;
        *(float4*)(lr + 128) = v1;
    }
    __syncthreads();

    /* ---- softmax + candidate extraction; each wave owns 16 tokens ---- */
    for (int r16 = 0; r16 < 16; ++r16) {
        const int row  = wv * 16 + r16;
        const int gtok = tok0 + row;
        float4 v = *(const float4*)(lgf + (size_t)row * 260 + lane * 4);
        float vv[4] = {v.x, v.y, v.z, v.w};

        float m = fmaxf(fmaxf(vv[0], vv[1]), fmaxf(vv[2], vv[3]));
        #pragma unroll
        for (int off = 32; off >= 1; off >>= 1)
            m = fmaxf(m, __shfl_xor(m, off));

        float s = expf(vv[0] - m) + expf(vv[1] - m)
                + expf(vv[2] - m) + expf(vv[3] - m);
        #pragma unroll
        for (int off = 32; off >= 1; off >>= 1)
            s += __shfl_xor(s, off);

        int   taken = 0;
        int   ncand = 0;
        float s8    = 0.0f;
        int   my_ci = 1 << 30;
        for (int it = 0; it < MAXC; ++it) {
            float bv = -INFINITY;
            int   bi = 1 << 30;
            #pragma unroll
            for (int j = 0; j < 4; ++j) {
                float cv = ((taken >> j) & 1) ? -INFINITY : vv[j];
                int   ci = lane * 4 + j;
                if (cv > bv || (cv == bv && ci < bi)) { bv = cv; bi = ci; }
            }
            #pragma unroll
            for (int off = 32; off >= 1; off >>= 1) {
                float ov = __shfl_xor(bv, off);
                int   oi = __shfl_xor(bi, off);
                if (ov > bv || (ov == bv && oi < bi)) { bv = ov; bi = oi; }
            }
            if (it == 7) s8 = bv;
            if (it >= 8 && bv < s8 - DELTA) break;   /* wave-uniform */
            if (lane == it) my_ci = bi;
            if ((bi >> 2) == lane) taken |= 1 << (bi & 3);
            ncand = it + 1;
        }

        if (lane < ncand) wsCand[gtok * 16 + lane] = my_ci;
        if (lane == 0) {
            wsCnt[gtok]  = ncand;
            wsM[gtok]    = m;
            wsInvs[gtok] = 1.0f / s;
        }
    }
}

/* K2: one WAVE per token (64-thread blocks, no reg cap -> xv stays in VGPRs). */
__global__ __launch_bounds__(64, 1)
void gate_repair(const float* __restrict__ x,
                 const float* __restrict__ w,
                 const int* __restrict__ wsCand,
                 const int* __restrict__ wsCnt,
                 const float* __restrict__ wsM,
                 const float* __restrict__ wsInvs,
                 float* __restrict__ outw,
                 float* __restrict__ outi)
{
    const int lane = threadIdx.x;
    const int gtok = blockIdx.x;

    const int   nc   = wsCnt[gtok];
    const float m    = wsM[gtok];
    const float invs = wsInvs[gtok];
    int my_ci = (lane < nc) ? wsCand[gtok * 16 + lane] : (1 << 30);

    const float* xrow = x + (size_t)gtok * DIM + lane * 4;
    float4 xv[28];
    #pragma unroll
    for (int j = 0; j < 28; ++j)
        xv[j] = *(const float4*)(xrow + j * 256);

    double ev = -1.0e300;
    for (int c = 0; c < nc; ++c) {
        const int e = __shfl(my_ci, c);
        const float* wrow = w + (size_t)e * DIM + lane * 4;
        double a0 = 0.0, a1 = 0.0, a2 = 0.0, a3 = 0.0;
        #pragma unroll
        for (int j = 0; j < 28; j += 4) {
            float4 q0 = *(const float4*)(wrow + (j + 0) * 256);
            float4 q1 = *(const float4*)(wrow + (j + 1) * 256);
            float4 q2 = *(const float4*)(wrow + (j + 2) * 256);
            float4 q3 = *(const float4*)(wrow + (j + 3) * 256);
            a0 = fma((double)xv[j + 0].x, (double)q0.x, a0);
            a0 = fma((double)xv[j + 0].y, (double)q0.y, a0);
            a0 = fma((double)xv[j + 0].z, (double)q0.z, a0);
            a0 = fma((double)xv[j + 0].w, (double)q0.w, a0);
            a1 = fma((double)xv[j + 1].x, (double)q1.x, a1);
            a1 = fma((double)xv[j + 1].y, (double)q1.y, a1);
            a1 = fma((double)xv[j + 1].z, (double)q1.z, a1);
            a1 = fma((double)xv[j + 1].w, (double)q1.w, a1);
            a2 = fma((double)xv[j + 2].x, (double)q2.x, a2);
            a2 = fma((double)xv[j + 2].y, (double)q2.y, a2);
            a2 = fma((double)xv[j + 2].z, (double)q2.z, a2);
            a2 = fma((double)xv[j + 2].w, (double)q2.w, a2);
            a3 = fma((double)xv[j + 3].x, (double)q3.x, a3);
            a3 = fma((double)xv[j + 3].y, (double)q3.y, a3);
            a3 = fma((double)xv[j + 3].z, (double)q3.z, a3);
            a3 = fma((double)xv[j + 3].w, (double)q3.w, a3);
        }
        double tot = (a0 + a1) + (a2 + a3);
        #pragma unroll
        for (int off = 32; off >= 1; off >>= 1)
            tot += __shfl_xor(tot, off);
        if (lane == c) ev = tot;
    }

    for (int it = 0; it < TK; ++it) {
        double bv2 = ev;
        int    bi2 = my_ci;
        int    bs2 = lane;
        #pragma unroll
        for (int off = 32; off >= 1; off >>= 1) {
            double ov = __shfl_xor(bv2, off);
            int    oi = __shfl_xor(bi2, off);
            int    os = __shfl_xor(bs2, off);
            if (ov > bv2 || (ov == bv2 && oi < bi2)) {
                bv2 = ov; bi2 = oi; bs2 = os;
            }
        }
        if (lane == it) {
            outw[(size_t)gtok * TK + it] = expf((float)bv2 - m) * invs;
            outi[(size_t)gtok * TK + it] = (float)bi2;
        }
        if (lane == bs2) ev = -1.0e300;
    }
}

extern "C" void kernel_launch(void* const* d_in, const int* in_sizes, int n_in,
                              void* d_out, int out_size, void* d_ws, size_t ws_size,
                              hipStream_t stream) {
    const float* x = (const float*)d_in[0];
    const float* w = (const float*)d_in[1];
    float* outw = (float*)d_out;
    float* outi = outw + (size_t)TOKENS * TK;
    char* wsb = (char*)d_ws;
    int*   wsCand = (int*)(wsb + WS_CAND);
    int*   wsCnt  = (int*)(wsb + WS_CNT);
    float* wsM    = (float*)(wsb + WS_M);
    float* wsInvs = (float*)(wsb + WS_INVS);

    gate_gemm<<<dim3(TOKENS / BM), dim3(256), K1_LDS_BYTES, stream>>>(
        x, w, wsCand, wsCnt, wsM, wsInvs);
    gate_repair<<<dim3(TOKENS), dim3(64), 0, stream>>>(
        x, w, wsCand, wsCnt, wsM, wsInvs, outw, outi);
}

// Round 10
// 1849.567 us; speedup vs baseline: 4.6972x; 4.6972x over previous
//
#include <hip/hip_runtime.h>
#include <math.h>

#define TOKENS 16384
#define DIM    7168
#define NEXP   256
#define TK     8
#define BM     64
#define BK     32
#define NKT    (DIM / BK)   /* 224 */
#define DELTA  8.0e-3f
#define MAXC   12

/* K1 LDS (floats), all linear for global_load_lds:
   X[2][64][32]    @0     (2048 fl/buf)  : token-major, k-minor
   W[2][8][256][4] @4096  (8192 fl/buf)  : kg-major, expert, 4k  (16B-granular
                                           transpose done via global addressing)
   total 20480 fl = 81920 B -> 1 block/CU. Epilogue overlay 64x260 fl fits. */
#define XOFF(b) ((b) * 2048)
#define WOFF(b) (4096 + (b) * 8192)
#define K1_LDS_BYTES 81920

/* ws layout (bytes): cand[16384][16] ints, cnt, m, invs */
#define WS_CAND 0
#define WS_CNT  (TOKENS * 16 * 4)
#define WS_M    (WS_CNT + TOKENS * 4)
#define WS_INVS (WS_M + TOKENS * 4)

__device__ __forceinline__ void gload16(const float* g, float* l) {
    __builtin_amdgcn_global_load_lds(
        (const __attribute__((address_space(1))) void*)g,
        (__attribute__((address_space(3))) void*)l, 16, 0, 0);
}

__global__ __launch_bounds__(256)
void gate_gemm(const float* __restrict__ x, const float* __restrict__ w,
               int* __restrict__ wsCand, int* __restrict__ wsCnt,
               float* __restrict__ wsM, float* __restrict__ wsInvs)
{
    extern __shared__ __align__(16) float smem[];
    const int t    = threadIdx.x;
    const int tx   = t & 31;     /* expert cols tx + 32j, j<8 */
    const int ty   = t >> 5;     /* token rows ty*8 + i       */
    const int lane = t & 63;
    const int wv   = t >> 6;
    const int tok0 = blockIdx.x * BM;

    /* staging lane decode (global side is per-lane; LDS side wave-uniform) */
    const int kpart = lane & 7;      /* X: 4-float chunk within k-row     */
    const int xsub  = lane >> 3;     /* X: row within 8-row group         */

/* X: 2 issues/wave (u=0,1): rows (wv*2+u)*8+xsub, LDS base (wv*2+u)*256.
   W: 8 issues/wave (v): chunk c=wv*8+v, kg=c>>2, eb=c&3, lane -> expert
      eb*64+lane, LDS base kg*1024+eb*256.  All 16B loads, linear LDS. */
#define STAGE(kt, buf) do {                                             \
    _Pragma("unroll")                                                   \
    for (int u = 0; u < 2; ++u) {                                       \
        const int row = (wv * 2 + u) * 8 + xsub;                        \
        gload16(x + (size_t)(tok0 + row) * DIM + (kt) * BK + kpart * 4, \
                smem + XOFF(buf) + (wv * 2 + u) * 256);                 \
    }                                                                   \
    _Pragma("unroll")                                                   \
    for (int v = 0; v < 8; ++v) {                                       \
        const int c  = wv * 8 + v;                                      \
        const int kg = c >> 2, eb = c & 3;                              \
        gload16(w + (size_t)(eb * 64 + lane) * DIM + (kt) * BK + kg * 4,\
                smem + WOFF(buf) + kg * 1024 + eb * 256);               \
    }                                                                   \
} while (0)

    float acc[8][8];   /* [token i][expert col j] -> logit[ty*8+i][tx+32j] */
    #pragma unroll
    for (int i = 0; i < 8; ++i)
        #pragma unroll
        for (int j = 0; j < 8; ++j)
            acc[i][j] = 0.0f;

    STAGE(0, 0);
    __syncthreads();

    for (int kt = 0; kt < NKT; ++kt) {
        const int cur = kt & 1;
        if (kt + 1 < NKT) STAGE(kt + 1, cur ^ 1);
        const float* Xb = smem + XOFF(cur) + ty * 8 * 32;
        const float* Wb = smem + WOFF(cur) + tx * 4;
        #pragma unroll
        for (int kg = 0; kg < 8; ++kg) {
            float4 xf[8];   /* wave-broadcast reads (2 addrs, free) */
            #pragma unroll
            for (int i = 0; i < 8; ++i)
                xf[i] = *(const float4*)(Xb + i * 32 + kg * 4);
            #pragma unroll
            for (int j = 0; j < 8; ++j) {
                /* contiguous 512B across half-wave + broadcast: conflict-free */
                float4 wf = *(const float4*)(Wb + kg * 1024 + j * 128);
                #pragma unroll
                for (int i = 0; i < 8; ++i) {
                    acc[i][j] = fmaf(xf[i].x, wf.x, acc[i][j]);
                    acc[i][j] = fmaf(xf[i].y, wf.y, acc[i][j]);
                    acc[i][j] = fmaf(xf[i].z, wf.z, acc[i][j]);
                    acc[i][j] = fmaf(xf[i].w, wf.w, acc[i][j]);
                }
            }
        }
        __syncthreads();
    }

    /* ---- logits to LDS overlay [64][260] (b32 stores, bank-spread) ---- */
    float* lgf = smem;
    #pragma unroll
    for (int i = 0; i < 8; ++i)
        #pragma unroll
        for (int j = 0; j < 8; ++j)
            lgf[(ty * 8 + i) * 260 + tx + 32 * j] = acc[i][j];
    __syncthreads();

    /* ---- softmax + candidate extraction; each wave owns 16 tokens ---- */
    for (int r16 = 0; r16 < 16; ++r16) {
        const int row  = wv * 16 + r16;
        const int gtok = tok0 + row;
        float4 v = *(const float4*)(lgf + (size_t)row * 260 + lane * 4);
        float vv[4] = {v.x, v.y, v.z, v.w};

        float m = fmaxf(fmaxf(vv[0], vv[1]), fmaxf(vv[2], vv[3]));
        #pragma unroll
        for (int off = 32; off >= 1; off >>= 1)
            m = fmaxf(m, __shfl_xor(m, off));

        float s = expf(vv[0] - m) + expf(vv[1] - m)
                + expf(vv[2] - m) + expf(vv[3] - m);
        #pragma unroll
        for (int off = 32; off >= 1; off >>= 1)
            s += __shfl_xor(s, off);

        int   taken = 0;
        int   ncand = 0;
        float s8    = 0.0f;
        int   my_ci = 1 << 30;
        for (int it = 0; it < MAXC; ++it) {
            float bv = -INFINITY;
            int   bi = 1 << 30;
            #pragma unroll
            for (int j = 0; j < 4; ++j) {
                float cv = ((taken >> j) & 1) ? -INFINITY : vv[j];
                int   ci = lane * 4 + j;
                if (cv > bv || (cv == bv && ci < bi)) { bv = cv; bi = ci; }
            }
            #pragma unroll
            for (int off = 32; off >= 1; off >>= 1) {
                float ov = __shfl_xor(bv, off);
                int   oi = __shfl_xor(bi, off);
                if (ov > bv || (ov == bv && oi < bi)) { bv = ov; bi = oi; }
            }
            if (it == 7) s8 = bv;
            if (it >= 8 && bv < s8 - DELTA) break;   /* wave-uniform */
            if (lane == it) my_ci = bi;
            if ((bi >> 2) == lane) taken |= 1 << (bi & 3);
            ncand = it + 1;
        }

        if (lane < ncand) wsCand[gtok * 16 + lane] = my_ci;
        if (lane == 0) {
            wsCnt[gtok]  = ncand;
            wsM[gtok]    = m;
            wsInvs[gtok] = 1.0f / s;
        }
    }
}

/* K2: one WAVE per token (64-thread blocks; xv stays in VGPRs). Proven. */
__global__ __launch_bounds__(64, 1)
void gate_repair(const float* __restrict__ x,
                 const float* __restrict__ w,
                 const int* __restrict__ wsCand,
                 const int* __restrict__ wsCnt,
                 const float* __restrict__ wsM,
                 const float* __restrict__ wsInvs,
                 float* __restrict__ outw,
                 float* __restrict__ outi)
{
    const int lane = threadIdx.x;
    const int gtok = blockIdx.x;

    const int   nc   = wsCnt[gtok];
    const float m    = wsM[gtok];
    const float invs = wsInvs[gtok];
    int my_ci = (lane < nc) ? wsCand[gtok * 16 + lane] : (1 << 30);

    const float* xrow = x + (size_t)gtok * DIM + lane * 4;
    float4 xv[28];
    #pragma unroll
    for (int j = 0; j < 28; ++j)
        xv[j] = *(const float4*)(xrow + j * 256);

    double ev = -1.0e300;
    for (int c = 0; c < nc; ++c) {
        const int e = __shfl(my_ci, c);
        const float* wrow = w + (size_t)e * DIM + lane * 4;
        double a0 = 0.0, a1 = 0.0, a2 = 0.0, a3 = 0.0;
        #pragma unroll
        for (int j = 0; j < 28; j += 4) {
            float4 q0 = *(const float4*)(wrow + (j + 0) * 256);
            float4 q1 = *(const float4*)(wrow + (j + 1) * 256);
            float4 q2 = *(const float4*)(wrow + (j + 2) * 256);
            float4 q3 = *(const float4*)(wrow + (j + 3) * 256);
            a0 = fma((double)xv[j + 0].x, (double)q0.x, a0);
            a0 = fma((double)xv[j + 0].y, (double)q0.y, a0);
            a0 = fma((double)xv[j + 0].z, (double)q0.z, a0);
            a0 = fma((double)xv[j + 0].w, (double)q0.w, a0);
            a1 = fma((double)xv[j + 1].x, (double)q1.x, a1);
            a1 = fma((double)xv[j + 1].y, (double)q1.y, a1);
            a1 = fma((double)xv[j + 1].z, (double)q1.z, a1);
            a1 = fma((double)xv[j + 1].w, (double)q1.w, a1);
            a2 = fma((double)xv[j + 2].x, (double)q2.x, a2);
            a2 = fma((double)xv[j + 2].y, (double)q2.y, a2);
            a2 = fma((double)xv[j + 2].z, (double)q2.z, a2);
            a2 = fma((double)xv[j + 2].w, (double)q2.w, a2);
            a3 = fma((double)xv[j + 3].x, (double)q3.x, a3);
            a3 = fma((double)xv[j + 3].y, (double)q3.y, a3);
            a3 = fma((double)xv[j + 3].z, (double)q3.z, a3);
            a3 = fma((double)xv[j + 3].w, (double)q3.w, a3);
        }
        double tot = (a0 + a1) + (a2 + a3);
        #pragma unroll
        for (int off = 32; off >= 1; off >>= 1)
            tot += __shfl_xor(tot, off);
        if (lane == c) ev = tot;
    }

    for (int it = 0; it < TK; ++it) {
        double bv2 = ev;
        int    bi2 = my_ci;
        int    bs2 = lane;
        #pragma unroll
        for (int off = 32; off >= 1; off >>= 1) {
            double ov = __shfl_xor(bv2, off);
            int    oi = __shfl_xor(bi2, off);
            int    os = __shfl_xor(bs2, off);
            if (ov > bv2 || (ov == bv2 && oi < bi2)) {
                bv2 = ov; bi2 = oi; bs2 = os;
            }
        }
        if (lane == it) {
            outw[(size_t)gtok * TK + it] = expf((float)bv2 - m) * invs;
            outi[(size_t)gtok * TK + it] = (float)bi2;
        }
        if (lane == bs2) ev = -1.0e300;
    }
}

extern "C" void kernel_launch(void* const* d_in, const int* in_sizes, int n_in,
                              void* d_out, int out_size, void* d_ws, size_t ws_size,
                              hipStream_t stream) {
    const float* x = (const float*)d_in[0];
    const float* w = (const float*)d_in[1];
    float* outw = (float*)d_out;
    float* outi = outw + (size_t)TOKENS * TK;
    char* wsb = (char*)d_ws;
    int*   wsCand = (int*)(wsb + WS_CAND);
    int*   wsCnt  = (int*)(wsb + WS_CNT);
    float* wsM    = (float*)(wsb + WS_M);
    float* wsInvs = (float*)(wsb + WS_INVS);

    gate_gemm<<<dim3(TOKENS / BM), dim3(256), K1_LDS_BYTES, stream>>>(
        x, w, wsCand, wsCnt, wsM, wsInvs);
    gate_repair<<<dim3(TOKENS), dim3(64), 0, stream>>>(
        x, w, wsCand, wsCnt, wsM, wsInvs, outw, outi);
}

// Round 11
// 1571.052 us; speedup vs baseline: 5.5299x; 1.1773x over previous
//
#include <hip/hip_runtime.h>
#include <math.h>

#define TOKENS 16384
#define DIM    7168
#define NEXP   256
#define TK     8
#define BM     64
#define BK     32
#define NKT    (DIM / BK)   /* 224 */
#define DELTA  8.0e-3f
#define MAXC   12

/* K1 LDS (floats), linear for global_load_lds:
   X[2][64][32]    @0     (2048 fl/buf)
   W[2][8][256][4] @4096  (8192 fl/buf)   total 20480 fl = 81920 B.
   No epilogue overlay needed (register-space softmax/extraction). */
#define XOFF(b) ((b) * 2048)
#define WOFF(b) (4096 + (b) * 8192)
#define K1_LDS_BYTES 81920

/* ws layout (bytes): cand[16384][16] ints, cnt, m, invs */
#define WS_CAND 0
#define WS_CNT  (TOKENS * 16 * 4)
#define WS_M    (WS_CNT + TOKENS * 4)
#define WS_INVS (WS_M + TOKENS * 4)

__device__ __forceinline__ void gload16(const float* g, float* l) {
    __builtin_amdgcn_global_load_lds(
        (const __attribute__((address_space(1))) void*)g,
        (__attribute__((address_space(3))) void*)l, 16, 0, 0);
}

__global__ __launch_bounds__(512, 2)
void gate_gemm(const float* __restrict__ x, const float* __restrict__ w,
               int* __restrict__ wsCand, int* __restrict__ wsCnt,
               float* __restrict__ wsM, float* __restrict__ wsInvs)
{
    extern __shared__ __align__(16) float smem[];
    const int t    = threadIdx.x;       /* 0..511, 8 waves */
    const int tx   = t & 31;            /* expert cols tx + 32j, j<8 */
    const int ty   = t >> 5;            /* 0..15 -> token rows ty*4 + i */
    const int lane = t & 63;
    const int wv   = t >> 6;            /* wave 0..7 */
    const int tok0 = blockIdx.x * BM;

/* X: 1 issue/wave: rows wv*8+(lane>>3), chunk lane&7 -> LDS fl wv*256+lane*4.
   W: 4 issues/wave: c=wv*4+v (0..31), kg=c>>2, eb=c&3, expert eb*64+lane,
      k-chunk kg -> LDS fl kg*1024+eb*256+lane*4.  All 16B, linear LDS. */
#define STAGE(kt, buf) do {                                               \
    gload16(x + (size_t)(tok0 + wv * 8 + (lane >> 3)) * DIM               \
                + (kt) * BK + (lane & 7) * 4,                             \
            smem + XOFF(buf) + wv * 256);                                 \
    _Pragma("unroll")                                                     \
    for (int v = 0; v < 4; ++v) {                                         \
        const int c  = wv * 4 + v;                                        \
        const int kg = c >> 2, eb = c & 3;                                \
        gload16(w + (size_t)(eb * 64 + lane) * DIM + (kt) * BK + kg * 4,  \
                smem + WOFF(buf) + kg * 1024 + eb * 256);                 \
    }                                                                     \
} while (0)

    float acc[4][8];   /* [token i][expert col j] -> logit[ty*4+i][tx+32j] */
    #pragma unroll
    for (int i = 0; i < 4; ++i)
        #pragma unroll
        for (int j = 0; j < 8; ++j)
            acc[i][j] = 0.0f;

    STAGE(0, 0);
    __syncthreads();

    for (int kt = 0; kt < NKT; ++kt) {
        const int cur = kt & 1;
        if (kt + 1 < NKT) STAGE(kt + 1, cur ^ 1);
        const float* Xb = smem + XOFF(cur) + ty * 4 * 32;
        const float* Wb = smem + WOFF(cur) + tx * 4;
        #pragma unroll
        for (int kg = 0; kg < 8; ++kg) {
            float4 xf[4];   /* 2-address wave-broadcast reads (free) */
            #pragma unroll
            for (int i = 0; i < 4; ++i)
                xf[i] = *(const float4*)(Xb + i * 32 + kg * 4);
            #pragma unroll
            for (int j = 0; j < 8; ++j) {
                /* contiguous 512B/half-wave + broadcast: conflict-free */
                float4 wf = *(const float4*)(Wb + kg * 1024 + j * 128);
                #pragma unroll
                for (int i = 0; i < 4; ++i) {
                    acc[i][j] = fmaf(xf[i].x, wf.x, acc[i][j]);
                    acc[i][j] = fmaf(xf[i].y, wf.y, acc[i][j]);
                    acc[i][j] = fmaf(xf[i].z, wf.z, acc[i][j]);
                    acc[i][j] = fmaf(xf[i].w, wf.w, acc[i][j]);
                }
            }
        }
        __syncthreads();
    }

    /* ---- register-space softmax + candidate extraction ----
       Token (ty*4+i)'s 256 logits live in one half-wave (32 lanes x 8 regs).
       All shuffles use offsets <=16: never cross the half-wave boundary.
       The two half-waves of a wave handle different tokens (divergent break
       is predicated per half). */
    const int hl = lane & 31;   /* lane within half-wave == tx */
    for (int i = 0; i < 4; ++i) {
        const int gtok = tok0 + ty * 4 + i;
        float vv[8];
        #pragma unroll
        for (int j = 0; j < 8; ++j) vv[j] = acc[i][j];

        float m = vv[0];
        #pragma unroll
        for (int j = 1; j < 8; ++j) m = fmaxf(m, vv[j]);
        #pragma unroll
        for (int off = 16; off >= 1; off >>= 1)
            m = fmaxf(m, __shfl_xor(m, off));

        float s = 0.0f;
        #pragma unroll
        for (int j = 0; j < 8; ++j) s += expf(vv[j] - m);
        #pragma unroll
        for (int off = 16; off >= 1; off >>= 1)
            s += __shfl_xor(s, off);

        int   taken = 0;
        int   ncand = 0;
        float s8    = 0.0f;
        int   my_ci = 1 << 30;
        for (int it = 0; it < MAXC; ++it) {
            float bv = -INFINITY;
            int   bi = 1 << 30;
            #pragma unroll
            for (int j = 0; j < 8; ++j) {
                float cv = ((taken >> j) & 1) ? -INFINITY : vv[j];
                int   ci = 32 * j + tx;
                if (cv > bv || (cv == bv && ci < bi)) { bv = cv; bi = ci; }
            }
            #pragma unroll
            for (int off = 16; off >= 1; off >>= 1) {
                float ov = __shfl_xor(bv, off);
                int   oi = __shfl_xor(bi, off);
                if (ov > bv || (ov == bv && oi < bi)) { bv = ov; bi = oi; }
            }
            if (it == 7) s8 = bv;
            if (it >= 8 && bv < s8 - DELTA) break;   /* uniform per half-wave */
            if (hl == it) my_ci = bi;
            if ((bi & 31) == hl) taken |= 1 << (bi >> 5);
            ncand = it + 1;
        }

        if (hl < ncand) wsCand[gtok * 16 + hl] = my_ci;
        if (hl == 0) {
            wsCnt[gtok]  = ncand;
            wsM[gtok]    = m;
            wsInvs[gtok] = 1.0f / s;
        }
    }
}

/* K2: one WAVE per token (64-thread blocks; xv stays in VGPRs). Proven. */
__global__ __launch_bounds__(64, 1)
void gate_repair(const float* __restrict__ x,
                 const float* __restrict__ w,
                 const int* __restrict__ wsCand,
                 const int* __restrict__ wsCnt,
                 const float* __restrict__ wsM,
                 const float* __restrict__ wsInvs,
                 float* __restrict__ outw,
                 float* __restrict__ outi)
{
    const int lane = threadIdx.x;
    const int gtok = blockIdx.x;

    const int   nc   = wsCnt[gtok];
    const float m    = wsM[gtok];
    const float invs = wsInvs[gtok];
    int my_ci = (lane < nc) ? wsCand[gtok * 16 + lane] : (1 << 30);

    const float* xrow = x + (size_t)gtok * DIM + lane * 4;
    float4 xv[28];
    #pragma unroll
    for (int j = 0; j < 28; ++j)
        xv[j] = *(const float4*)(xrow + j * 256);

    double ev = -1.0e300;
    for (int c = 0; c < nc; ++c) {
        const int e = __shfl(my_ci, c);
        const float* wrow = w + (size_t)e * DIM + lane * 4;
        double a0 = 0.0, a1 = 0.0, a2 = 0.0, a3 = 0.0;
        #pragma unroll
        for (int j = 0; j < 28; j += 4) {
            float4 q0 = *(const float4*)(wrow + (j + 0) * 256);
            float4 q1 = *(const float4*)(wrow + (j + 1) * 256);
            float4 q2 = *(const float4*)(wrow + (j + 2) * 256);
            float4 q3 = *(const float4*)(wrow + (j + 3) * 256);
            a0 = fma((double)xv[j + 0].x, (double)q0.x, a0);
            a0 = fma((double)xv[j + 0].y, (double)q0.y, a0);
            a0 = fma((double)xv[j + 0].z, (double)q0.z, a0);
            a0 = fma((double)xv[j + 0].w, (double)q0.w, a0);
            a1 = fma((double)xv[j + 1].x, (double)q1.x, a1);
            a1 = fma((double)xv[j + 1].y, (double)q1.y, a1);
            a1 = fma((double)xv[j + 1].z, (double)q1.z, a1);
            a1 = fma((double)xv[j + 1].w, (double)q1.w, a1);
            a2 = fma((double)xv[j + 2].x, (double)q2.x, a2);
            a2 = fma((double)xv[j + 2].y, (double)q2.y, a2);
            a2 = fma((double)xv[j + 2].z, (double)q2.z, a2);
            a2 = fma((double)xv[j + 2].w, (double)q2.w, a2);
            a3 = fma((double)xv[j + 3].x, (double)q3.x, a3);
            a3 = fma((double)xv[j + 3].y, (double)q3.y, a3);
            a3 = fma((double)xv[j + 3].z, (double)q3.z, a3);
            a3 = fma((double)xv[j + 3].w, (double)q3.w, a3);
        }
        double tot = (a0 + a1) + (a2 + a3);
        #pragma unroll
        for (int off = 32; off >= 1; off >>= 1)
            tot += __shfl_xor(tot, off);
        if (lane == c) ev = tot;
    }

    for (int it = 0; it < TK; ++it) {
        double bv2 = ev;
        int    bi2 = my_ci;
        int    bs2 = lane;
        #pragma unroll
        for (int off = 32; off >= 1; off >>= 1) {
            double ov = __shfl_xor(bv2, off);
            int    oi = __shfl_xor(bi2, off);
            int    os = __shfl_xor(bs2, off);
            if (ov > bv2 || (ov == bv2 && oi < bi2)) {
                bv2 = ov; bi2 = oi; bs2 = os;
            }
        }
        if (lane == it) {
            outw[(size_t)gtok * TK + it] = expf((float)bv2 - m) * invs;
            outi[(size_t)gtok * TK + it] = (float)bi2;
        }
        if (lane == bs2) ev = -1.0e300;
    }
}

extern "C" void kernel_launch(void* const* d_in, const int* in_sizes, int n_in,
                              void* d_out, int out_size, void* d_ws, size_t ws_size,
                              hipStream_t stream) {
    const float* x = (const float*)d_in[0];
    const float* w = (const float*)d_in[1];
    float* outw = (float*)d_out;
    float* outi = outw + (size_t)TOKENS * TK;
    char* wsb = (char*)d_ws;
    int*   wsCand = (int*)(wsb + WS_CAND);
    int*   wsCnt  = (int*)(wsb + WS_CNT);
    float* wsM    = (float*)(wsb + WS_M);
    float* wsInvs = (float*)(wsb + WS_INVS);

    gate_gemm<<<dim3(TOKENS / BM), dim3(512), K1_LDS_BYTES, stream>>>(
        x, w, wsCand, wsCnt, wsM, wsInvs);
    gate_repair<<<dim3(TOKENS), dim3(64), 0, stream>>>(
        x, w, wsCand, wsCnt, wsM, wsInvs, outw, outi);
}